// Round 4
// baseline (138.933 us; speedup 1.0000x reference)
//
#include <hip/hip_runtime.h>

#define Bsz 8
#define Cn  4
#define Hn  64
#define Wn  2048
#define HW  (Hn*Wn)

#define TW 64
#define TH 8
// 3-iteration dependence cone: +/-6 cols, +/-3 rows
#define BW 76              // TW+12
#define BH 14              // TH+6
#define NB (BW*BH)         // 1064

// Gaussian stencil exp(-(dh^2+dw^2)/(2*0.9^2)), center zeroed.
#define G1 0.53940824f
#define G2 0.29096127f
#define G4 0.08465836f
#define G5 0.04566536f

__device__ __forceinline__ float4 f4fma(float a, const float4& v, const float4& acc) {
    return make_float4(fmaf(a, v.x, acc.x), fmaf(a, v.y, acc.y),
                       fmaf(a, v.z, acc.z), fmaf(a, v.w, acc.w));
}

// Finish one pixel: compat/weights epilogue; FINAL -> planar global store,
// else softmax(Q_new) -> Sout[bidx]. Out-of-image pixels keep S = 0 (zero-pad).
template<bool FINAL>
__device__ __forceinline__ void finish_px(int gh, int gw, int bidx,
                                          const float4& ksm, const float4& app, float mc,
                                          const float* __restrict__ unary,
                                          float* __restrict__ outp,
                                          float4* __restrict__ Sout, size_t qbase,
                                          const float* wa, const float* wsm,
                                          const float* cw) {
    bool inimg = (gh >= 0) & (gh < Hn) & (gw >= 0) & (gw < Wn);
    if (inimg) {
        size_t p = (size_t)gh * Wn + gw;
        float wk0 = ksm.x * (wsm[0] + wa[0] * (app.x * mc));
        float wk1 = ksm.y * (wsm[1] + wa[1] * (app.y * mc));
        float wk2 = ksm.z * (wsm[2] + wa[2] * (app.z * mc));
        float wk3 = ksm.w * (wsm[3] + wa[3] * (app.w * mc));
        float q[4];
#pragma unroll
        for (int o = 0; o < 4; ++o) {
            float pw = cw[o * 4 + 0] * wk0 + cw[o * 4 + 1] * wk1 +
                       cw[o * 4 + 2] * wk2 + cw[o * 4 + 3] * wk3;
            q[o] = unary[qbase + p + (size_t)o * HW] - pw;
        }
        if (FINAL) {
#pragma unroll
            for (int o = 0; o < 4; ++o)
                outp[qbase + p + (size_t)o * HW] = q[o];
        } else {
            float mx = fmaxf(fmaxf(q[0], q[1]), fmaxf(q[2], q[3]));
            float e0 = __expf(q[0] - mx), e1 = __expf(q[1] - mx);
            float e2 = __expf(q[2] - mx), e3 = __expf(q[3] - mx);
            float inv = 1.0f / (e0 + e1 + e2 + e3);
            Sout[bidx] = make_float4(e0 * inv, e1 * inv, e2 * inv, e3 * inv);
        }
    } else if (!FINAL) {
        Sout[bidx] = make_float4(0.f, 0.f, 0.f, 0.f);
    }
}

// One CRF iteration over region RW x RH at tile-local origin (OY, OX),
// processed as vertical pixel pairs sharing the 4-row tap window.
template<int RW, int RH, int OY, int OX, bool FINAL>
__device__ __forceinline__ void do_iter(const float4* __restrict__ Sin,
                                        float4* __restrict__ Sout,
                                        const float4* __restrict__ X,
                                        const float* __restrict__ unary,
                                        float* __restrict__ outp,
                                        size_t qbase, int h0, int w0, int tid,
                                        const float* wa, const float* wsm,
                                        const float* cw) {
    const float Gt[3][5] = {
        {G5, G2, G1, G2, G5},
        {G4, G1, 0.f, G1, G4},
        {G5, G2, G1, G2, G5}};
    constexpr int P = RW * (RH / 2);
    for (int i = tid; i < P; i += 256) {
        int pr = i / RW;
        int pc = i - pr * RW;
        int r0 = OY + 2 * pr;           // tile-local row of px0
        int c  = OX + pc;
        int b0 = (r0 + 3) * BW + (c + 6);

        float4 xc0 = X[b0];
        float4 xc1 = X[b0 + BW];
        float4 ksm0 = make_float4(0,0,0,0), app0 = make_float4(0,0,0,0);
        float4 ksm1 = make_float4(0,0,0,0), app1 = make_float4(0,0,0,0);

#pragma unroll
        for (int j = 0; j < 4; ++j) {   // buffer row r0-1+j
            int rb = b0 + (j - 1) * BW;
            float4 s[5], x[5];
#pragma unroll
            for (int d = 0; d < 5; ++d) {
                s[d] = Sin[rb + d - 2];
                x[d] = X[rb + d - 2];
            }
#pragma unroll
            for (int d = 0; d < 5; ++d) {
                if (j <= 2 && !(j == 1 && d == 2)) {      // px0: dh = j-1
                    ksm0 = f4fma(Gt[j][d], s[d], ksm0);
                    float dx = x[d].x - xc0.x, dy = x[d].y - xc0.y, dz = x[d].z - xc0.z;
                    float bm = __expf(-2222.2222f * (dx*dx + dy*dy + dz*dz)) * x[d].w;
                    app0 = f4fma(bm, s[d], app0);
                }
                if (j >= 1 && !(j == 2 && d == 2)) {      // px1: dh = j-2
                    ksm1 = f4fma(Gt[j - 1][d], s[d], ksm1);
                    float dx = x[d].x - xc1.x, dy = x[d].y - xc1.y, dz = x[d].z - xc1.z;
                    float bm = __expf(-2222.2222f * (dx*dx + dy*dy + dz*dz)) * x[d].w;
                    app1 = f4fma(bm, s[d], app1);
                }
            }
        }

        int gw = w0 + c;
        int gh0 = h0 + r0;
        finish_px<FINAL>(gh0,     gw, b0,      ksm0, app0, xc0.w, unary, outp, Sout,
                         qbase, wa, wsm, cw);
        finish_px<FINAL>(gh0 + 1, gw, b0 + BW, ksm1, app1, xc1.w, unary, outp, Sout,
                         qbase, wa, wsm, cw);
    }
}

__global__ __launch_bounds__(256, 3) void crf_fused(const float* __restrict__ unary,
                                                    const float* __restrict__ xyz,
                                                    const float* __restrict__ mask,
                                                    const float* __restrict__ wa_g,
                                                    const float* __restrict__ wsm_g,
                                                    const float* __restrict__ cw_g,
                                                    float* __restrict__ outp) {
    __shared__ float4 SA[NB];
    __shared__ float4 SB[NB];
    __shared__ float4 X[NB];

    const int tid = threadIdx.x;
    const int w0 = blockIdx.x * TW;
    const int h0 = blockIdx.y * TH;
    const int b  = blockIdx.z;

    const size_t qbase = (size_t)b * Cn * HW;
    const size_t xbase = (size_t)b * 3 * HW;
    const size_t mbase = (size_t)b * HW;

    float wa[4], wsm[4], cw[16];
#pragma unroll
    for (int k = 0; k < 4; ++k) { wa[k] = wa_g[k]; wsm[k] = wsm_g[k]; }
#pragma unroll
    for (int k = 0; k < 16; ++k) cw[k] = cw_g[k];

    // ---- stage softmax(unary) + (xyz,mask) for the full cone halo ----
    for (int i = tid; i < NB; i += 256) {
        int br = i / BW;
        int bc = i - br * BW;
        int gh = h0 + br - 3;
        int gw = w0 + bc - 6;
        float4 s  = make_float4(0.f, 0.f, 0.f, 0.f);
        float4 xm = make_float4(0.f, 0.f, 0.f, 0.f);
        if (gh >= 0 && gh < Hn && gw >= 0 && gw < Wn) {
            size_t p = (size_t)gh * Wn + gw;
            float q0 = unary[qbase + p];
            float q1 = unary[qbase + p + HW];
            float q2 = unary[qbase + p + 2 * HW];
            float q3 = unary[qbase + p + 3 * HW];
            float mx = fmaxf(fmaxf(q0, q1), fmaxf(q2, q3));
            float e0 = __expf(q0 - mx), e1 = __expf(q1 - mx);
            float e2 = __expf(q2 - mx), e3 = __expf(q3 - mx);
            float inv = 1.0f / (e0 + e1 + e2 + e3);
            s = make_float4(e0 * inv, e1 * inv, e2 * inv, e3 * inv);
            xm = make_float4(xyz[xbase + p], xyz[xbase + p + HW],
                             xyz[xbase + p + 2 * HW], mask[mbase + p]);
        }
        SA[i] = s;
        X[i] = xm;
    }
    __syncthreads();

    do_iter<72, 12, -2, -4, false>(SA, SB, X, unary, nullptr, qbase, h0, w0, tid, wa, wsm, cw);
    __syncthreads();
    do_iter<68, 10, -1, -2, false>(SB, SA, X, unary, nullptr, qbase, h0, w0, tid, wa, wsm, cw);
    __syncthreads();
    do_iter<64,  8,  0,  0, true >(SA, nullptr, X, unary, outp, qbase, h0, w0, tid, wa, wsm, cw);
}

extern "C" void kernel_launch(void* const* d_in, const int* in_sizes, int n_in,
                              void* d_out, int out_size, void* d_ws, size_t ws_size,
                              hipStream_t stream) {
    const float* unary  = (const float*)d_in[0];
    const float* xyz    = (const float*)d_in[1];
    const float* mask   = (const float*)d_in[2];
    const float* wa     = (const float*)d_in[3];
    const float* wsm    = (const float*)d_in[4];
    const float* compat = (const float*)d_in[5];
    float* outp = (float*)d_out;

    dim3 grid(Wn / TW, Hn / TH, Bsz), blk(256);
    crf_fused<<<grid, blk, 0, stream>>>(unary, xyz, mask, wa, wsm, compat, outp);
}

// Round 5
// 123.387 us; speedup vs baseline: 1.1260x; 1.1260x over previous
//
#include <hip/hip_runtime.h>
#include <hip/hip_fp16.h>

#define Bsz 8
#define Cn  4
#define Hn  64
#define Wn  2048
#define HW  (Hn*Wn)

#define TW 64
#define TH 8
// 3-iteration cone: +/-6 cols, +/-3 rows
#define BW 76
#define BH 14
#define NB (BW*BH)          // 1064
// region-1 (iteration-1 output region): 72 x 12 at tile-local (-2,-4)
#define R1W 72
#define R1H 12
#define NR1 (R1W*R1H)       // 864

#define XBYTES (NB*16)      // 17024 (== SA+SB bytes, overlaid)
#define BBYTES (4*NR1*8)    // 27648

// Gaussian stencil exp(-(dh^2+dw^2)/(2*0.9^2)), center zeroed.
#define G1 0.53940824f
#define G2 0.29096127f
#define G4 0.08465836f
#define G5 0.04566536f

struct Half4 { __half2 lo, hi; };

__device__ __forceinline__ __half hsel(const Half4& h, int k) {
    return (k == 0) ? __low2half(h.lo) : (k == 1) ? __high2half(h.lo)
         : (k == 2) ? __low2half(h.hi) : __high2half(h.hi);
}

__device__ __forceinline__ __half2 GH2(int r, int d) {
    const float Gt[3][5] = {
        {G5, G2, G1, G2, G5},
        {G4, G1, 0.f, G1, G4},
        {G5, G2, G1, G2, G5}};
    return __float2half2_rn(Gt[r][d]);
}

template<bool FINAL>
__device__ __forceinline__ void finish_px(int gh, int gw, int bi,
        __half2 ka, __half2 kb, __half2 aa, __half2 ab, __half mch,
        const float* __restrict__ unary, float* __restrict__ outp,
        Half4* __restrict__ Sout, size_t qbase,
        const float* wa, const float* wsm, const float* cw) {
    bool inimg = (gh >= 0) & (gh < Hn) & (gw >= 0) & (gw < Wn);
    if (inimg) {
        size_t p = (size_t)gh * Wn + gw;
        float ksm[4] = {__low2float(ka), __high2float(ka), __low2float(kb), __high2float(kb)};
        float app[4] = {__low2float(aa), __high2float(aa), __low2float(ab), __high2float(ab)};
        float mc = __half2float(mch);
        float wk[4];
#pragma unroll
        for (int c = 0; c < 4; ++c)
            wk[c] = ksm[c] * (wsm[c] + wa[c] * (app[c] * mc));
        float q[4];
#pragma unroll
        for (int o = 0; o < 4; ++o) {
            float pw = cw[o*4+0]*wk[0] + cw[o*4+1]*wk[1] + cw[o*4+2]*wk[2] + cw[o*4+3]*wk[3];
            q[o] = unary[qbase + p + (size_t)o * HW] - pw;
        }
        if (FINAL) {
#pragma unroll
            for (int o = 0; o < 4; ++o)
                outp[qbase + p + (size_t)o * HW] = q[o];
        } else {
            float mx = fmaxf(fmaxf(q[0], q[1]), fmaxf(q[2], q[3]));
            float e0 = __expf(q[0]-mx), e1 = __expf(q[1]-mx);
            float e2 = __expf(q[2]-mx), e3 = __expf(q[3]-mx);
            float inv = 1.0f / (e0 + e1 + e2 + e3);
            Half4 s; s.lo = __floats2half2_rn(e0*inv, e1*inv);
            s.hi = __floats2half2_rn(e2*inv, e3*inv);
            Sout[bi] = s;
        }
    } else if (!FINAL) {
        Half4 z; z.lo = __float2half2_rn(0.f); z.hi = z.lo;
        Sout[bi] = z;
    }
}

template<int RW, int RH, int OY, int OX, bool FINAL>
__device__ __forceinline__ void do_iter(const Half4* __restrict__ Sin,
                                        Half4* __restrict__ Sout,
                                        const Half4* __restrict__ BETA,
                                        const float* __restrict__ unary,
                                        float* __restrict__ outp,
                                        size_t qbase, int h0, int w0, int tid,
                                        const float* wa, const float* wsm,
                                        const float* cw) {
    constexpr int P = RW * (RH / 2);
    for (int i = tid; i < P; i += 256) {
        int pr = i / RW;
        int pc = i - pr * RW;
        const int r0 = OY + 2 * pr;            // tile-local row of px0
        const int c  = OX + pc;
        const int bi0 = (r0 + 3) * BW + (c + 6);
        const int p1  = (r0 + 2) * R1W + (c + 4);

        Half4 B0[4], B1[4];
#pragma unroll
        for (int g = 0; g < 4; ++g) {
            B0[g] = BETA[g * NR1 + p1];
            B1[g] = BETA[g * NR1 + p1 + R1W];
        }

        const __half2 z2 = __float2half2_rn(0.f);
        __half2 k0a = z2, k0b = z2, a0a = z2, a0b = z2;
        __half2 k1a = z2, k1b = z2, a1a = z2, a1b = z2;

#pragma unroll
        for (int j = 0; j < 4; ++j) {          // buffer row bi0 + (j-1)*BW
            const int rb = bi0 + (j - 1) * BW;
            Half4 s[5];
#pragma unroll
            for (int d = 0; d < 5; ++d) s[d] = Sin[rb + d - 2];
#pragma unroll
            for (int d = 0; d < 5; ++d) {
                if (j <= 2 && !(j == 1 && d == 2)) {       // px0: dh = j-1
                    const int t = (j == 0) ? d : (j == 1) ? ((d < 2) ? 5 + d : 4 + d) : 9 + d;
                    const __half2 g2 = GH2(j, d);
                    k0a = __hfma2(g2, s[d].lo, k0a);
                    k0b = __hfma2(g2, s[d].hi, k0b);
                    const __half2 bm2 = __half2half2(hsel(B0[t >> 2], t & 3));
                    a0a = __hfma2(bm2, s[d].lo, a0a);
                    a0b = __hfma2(bm2, s[d].hi, a0b);
                }
                if (j >= 1 && !(j == 2 && d == 2)) {       // px1: dh = j-2
                    const int t = (j == 1) ? d : (j == 2) ? ((d < 2) ? 5 + d : 4 + d) : 9 + d;
                    const __half2 g2 = GH2(j - 1, d);
                    k1a = __hfma2(g2, s[d].lo, k1a);
                    k1b = __hfma2(g2, s[d].hi, k1b);
                    const __half2 bm2 = __half2half2(hsel(B1[t >> 2], t & 3));
                    a1a = __hfma2(bm2, s[d].lo, a1a);
                    a1b = __hfma2(bm2, s[d].hi, a1b);
                }
            }
        }

        const int gw = w0 + c;
        const int gh0 = h0 + r0;
        finish_px<FINAL>(gh0,     gw, bi0,      k0a, k0b, a0a, a0b, hsel(B0[3], 2),
                         unary, outp, Sout, qbase, wa, wsm, cw);
        finish_px<FINAL>(gh0 + 1, gw, bi0 + BW, k1a, k1b, a1a, a1b, hsel(B1[3], 2),
                         unary, outp, Sout, qbase, wa, wsm, cw);
    }
}

__global__ __launch_bounds__(256, 3) void crf_fused(const float* __restrict__ unary,
                                                    const float* __restrict__ xyz,
                                                    const float* __restrict__ mask,
                                                    const float* __restrict__ wa_g,
                                                    const float* __restrict__ wsm_g,
                                                    const float* __restrict__ cw_g,
                                                    float* __restrict__ outp) {
    __shared__ __align__(16) unsigned char LDS_[XBYTES + BBYTES];   // 44672 B
    Half4*  SA   = (Half4*)LDS_;                 // NB half4
    Half4*  SB   = SA + NB;                      // NB half4
    float4* XBUF = (float4*)LDS_;                // overlays SA+SB, phases 1-2 only
    Half4*  BETA = (Half4*)(LDS_ + XBYTES);      // [4][NR1]

    const int tid = threadIdx.x;
    const int w0 = blockIdx.x * TW;
    const int h0 = blockIdx.y * TH;
    const int b  = blockIdx.z;

    const size_t qbase = (size_t)b * Cn * HW;
    const size_t xbase = (size_t)b * 3 * HW;
    const size_t mbase = (size_t)b * HW;

    float wa[4], wsm[4], cw[16];
#pragma unroll
    for (int k = 0; k < 4; ++k) { wa[k] = wa_g[k]; wsm[k] = wsm_g[k]; }
#pragma unroll
    for (int k = 0; k < 16; ++k) cw[k] = cw_g[k];

    // ---- phase 1: stage packed (xyz, mask) halo ----
    for (int i = tid; i < NB; i += 256) {
        int br = i / BW, bc = i - br * BW;
        int gh = h0 + br - 3, gw = w0 + bc - 6;
        float4 xm = make_float4(0.f, 0.f, 0.f, 0.f);
        if (gh >= 0 && gh < Hn && gw >= 0 && gw < Wn) {
            size_t p = (size_t)gh * Wn + gw;
            xm = make_float4(xyz[xbase + p], xyz[xbase + p + HW],
                             xyz[xbase + p + 2 * HW], mask[mbase + p]);
        }
        XBUF[i] = xm;
    }
    __syncthreads();

    // ---- phase 2: iteration-invariant beta*mask (+ center mask) -> BETA ----
    for (int p = tid; p < NR1; p += 256) {
        int r1 = p / R1W, c1 = p - r1 * R1W;
        int bi = (r1 + 1) * BW + (c1 + 2);
        float4 xc = XBUF[bi];
        float bm[14];
        int t = 0;
#pragma unroll
        for (int dh = -1; dh <= 1; ++dh) {
#pragma unroll
            for (int dw = -2; dw <= 2; ++dw) {
                if (dh == 0 && dw == 0) continue;
                float4 xn = XBUF[bi + dh * BW + dw];
                float dx = xn.x - xc.x, dy = xn.y - xc.y, dz = xn.z - xc.z;
                bm[t++] = __expf(-2222.2222f * (dx*dx + dy*dy + dz*dz)) * xn.w;
            }
        }
        Half4 g0, g1, g2, g3;
        g0.lo = __floats2half2_rn(bm[0],  bm[1]);  g0.hi = __floats2half2_rn(bm[2],  bm[3]);
        g1.lo = __floats2half2_rn(bm[4],  bm[5]);  g1.hi = __floats2half2_rn(bm[6],  bm[7]);
        g2.lo = __floats2half2_rn(bm[8],  bm[9]);  g2.hi = __floats2half2_rn(bm[10], bm[11]);
        g3.lo = __floats2half2_rn(bm[12], bm[13]); g3.hi = __floats2half2_rn(xc.w, 0.f);
        BETA[0 * NR1 + p] = g0; BETA[1 * NR1 + p] = g1;
        BETA[2 * NR1 + p] = g2; BETA[3 * NR1 + p] = g3;
    }
    __syncthreads();

    // ---- phase 3: stage softmax(unary) as fp16x4 into SA (X is dead) ----
    for (int i = tid; i < NB; i += 256) {
        int br = i / BW, bc = i - br * BW;
        int gh = h0 + br - 3, gw = w0 + bc - 6;
        Half4 s; s.lo = __float2half2_rn(0.f); s.hi = s.lo;
        if (gh >= 0 && gh < Hn && gw >= 0 && gw < Wn) {
            size_t p = (size_t)gh * Wn + gw;
            float q0 = unary[qbase + p];
            float q1 = unary[qbase + p + HW];
            float q2 = unary[qbase + p + 2 * HW];
            float q3 = unary[qbase + p + 3 * HW];
            float mx = fmaxf(fmaxf(q0, q1), fmaxf(q2, q3));
            float e0 = __expf(q0 - mx), e1 = __expf(q1 - mx);
            float e2 = __expf(q2 - mx), e3 = __expf(q3 - mx);
            float inv = 1.0f / (e0 + e1 + e2 + e3);
            s.lo = __floats2half2_rn(e0 * inv, e1 * inv);
            s.hi = __floats2half2_rn(e2 * inv, e3 * inv);
        }
        SA[i] = s;
    }
    __syncthreads();

    do_iter<R1W, R1H, -2, -4, false>(SA, SB, BETA, unary, nullptr, qbase, h0, w0, tid, wa, wsm, cw);
    __syncthreads();
    do_iter<68, 10, -1, -2, false>(SB, SA, BETA, unary, nullptr, qbase, h0, w0, tid, wa, wsm, cw);
    __syncthreads();
    do_iter<64, 8, 0, 0, true>(SA, nullptr, BETA, unary, outp, qbase, h0, w0, tid, wa, wsm, cw);
}

extern "C" void kernel_launch(void* const* d_in, const int* in_sizes, int n_in,
                              void* d_out, int out_size, void* d_ws, size_t ws_size,
                              hipStream_t stream) {
    const float* unary  = (const float*)d_in[0];
    const float* xyz    = (const float*)d_in[1];
    const float* mask   = (const float*)d_in[2];
    const float* wa     = (const float*)d_in[3];
    const float* wsm    = (const float*)d_in[4];
    const float* compat = (const float*)d_in[5];
    float* outp = (float*)d_out;

    dim3 grid(Wn / TW, Hn / TH, Bsz), blk(256);
    crf_fused<<<grid, blk, 0, stream>>>(unary, xyz, mask, wa, wsm, compat, outp);
}